// Round 1
// baseline (3404.952 us; speedup 1.0000x reference)
//
#include <hip/hip_runtime.h>
#include <hip/hip_bf16.h>

typedef __attribute__((ext_vector_type(8))) short short8;
typedef __attribute__((ext_vector_type(4))) float f32x4;

#define B_ 64
#define S_ 1024
#define I_ 256
#define H_ 512
#define O_ 256
#define M_ (B_ * S_)   // 65536 rows everywhere

// ---------- helpers ----------
__device__ __forceinline__ ushort bf16_rne(float f) {
  unsigned u = __float_as_uint(f);
  return (ushort)((u + 0x7FFFu + ((u >> 16) & 1u)) >> 16);
}
__device__ __forceinline__ float bf16_f(ushort s) {
  return __uint_as_float(((unsigned)s) << 16);
}
__device__ __forceinline__ void gll16(const void* g, void* l) {
  __builtin_amdgcn_global_load_lds((const __attribute__((address_space(1))) void*)g,
                                   (__attribute__((address_space(3))) void*)l, 16, 0, 0);
}
__device__ __forceinline__ float tanh_fast(float a) {
  a = fminf(fmaxf(a, -9.0f), 9.0f);
#if __has_builtin(__builtin_amdgcn_exp2f)
  float t = __builtin_amdgcn_exp2f(a * 2.8853900817779268f); // e^(2a)
#else
  float t = exp2f(a * 2.8853900817779268f);
#endif
#if __has_builtin(__builtin_amdgcn_rcpf)
  return (t - 1.0f) * __builtin_amdgcn_rcpf(t + 1.0f);
#else
  return (t - 1.0f) / (t + 1.0f);
#endif
}

// ---------- fp32 -> bf16 convert ----------
__global__ void cvt_kern(const float* __restrict__ in, ushort* __restrict__ out, long n) {
  long i = ((long)blockIdx.x * blockDim.x + threadIdx.x) * 4;
  const long stride = (long)gridDim.x * blockDim.x * 4;
  for (; i < n; i += stride) {
    const float4 v = *(const float4*)(in + i);
    ushort4 o;
    o.x = bf16_rne(v.x); o.y = bf16_rne(v.y); o.z = bf16_rne(v.z); o.w = bf16_rne(v.w);
    *(ushort4*)(out + i) = o;
  }
}

__global__ void biascomb_kern(const float* __restrict__ a, const float* __restrict__ b,
                              float* __restrict__ o) {
  int i = threadIdx.x;
  o[i] = a[i] + b[i];
}

// ---------- GEMM: C[M,N] = A[M,K] @ Wt[N,K]^T + bias ----------
// 128x128 tile, BK=32, 4 waves (2x2), 16x16x32 bf16 MFMA, global_load_lds staging.
template<bool OUT_F32>
__global__ __launch_bounds__(256) void gemm_kern(
    const ushort* __restrict__ A, const ushort* __restrict__ Wt,
    const float* __restrict__ bias, void* __restrict__ out,
    int M, int N, int K)
{
  __shared__ char smem[16384];   // [0,8K): A tile  [8K,16K): B tile; layout [kgrp][row][16B]
  const int tid = threadIdx.x;
  const int lane = tid & 63, wave = tid >> 6;
  const int wm = wave >> 1, wn = wave & 1;
  const int nt = N >> 7;
  const int bm = blockIdx.x / nt, bn = blockIdx.x % nt;
  const long m0 = (long)bm * 128, n0 = (long)bn * 128;

  f32x4 acc[4][4] = {};
  const int KT = K >> 5;
  for (int kt = 0; kt < KT; ++kt) {
    #pragma unroll
    for (int i = 0; i < 4; ++i) {
      const int c = wave * 4 + i;         // 0..15
      const int isB = c >> 3;
      const int cc = c & 7;
      const int kgrp = cc >> 1, rhalf = cc & 1;
      const int row = rhalf * 64 + lane;
      const ushort* src = (isB ? Wt + (n0 + row) * (long)K : A + (m0 + row) * (long)K)
                          + (long)kt * 32 + kgrp * 8;
      gll16(src, smem + isB * 8192 + kgrp * 2048 + rhalf * 1024);
    }
    __syncthreads();
    const char* Ab = smem + (lane >> 4) * 2048;
    const char* Bb = smem + 8192 + (lane >> 4) * 2048;
    short8 af[4], bf[4];
    #pragma unroll
    for (int i = 0; i < 4; ++i) {
      af[i] = *(const short8*)(Ab + (wm * 64 + i * 16 + (lane & 15)) * 16);
      bf[i] = *(const short8*)(Bb + (wn * 64 + i * 16 + (lane & 15)) * 16);
    }
    #pragma unroll
    for (int mi = 0; mi < 4; ++mi)
      #pragma unroll
      for (int ni = 0; ni < 4; ++ni)
        acc[mi][ni] = __builtin_amdgcn_mfma_f32_16x16x32_bf16(af[mi], bf[ni], acc[mi][ni], 0, 0, 0);
    __syncthreads();
  }
  #pragma unroll
  for (int ni = 0; ni < 4; ++ni) {
    const long n = n0 + wn * 64 + ni * 16 + (lane & 15);
    const float bv = bias[n];
    #pragma unroll
    for (int mi = 0; mi < 4; ++mi) {
      const long mrow = m0 + wm * 64 + mi * 16 + (lane >> 4) * 4;
      #pragma unroll
      for (int r = 0; r < 4; ++r) {
        const float v = acc[mi][ni][r] + bv;
        if (OUT_F32) ((float*)out)[(mrow + r) * (long)N + n] = v;
        else         ((ushort*)out)[(mrow + r) * (long)N + n] = bf16_rne(v);
      }
    }
  }
}

// ---------- recurrence: h_t = tanh(xu_t + W h_{t-1}) ----------
// 4 WGs x 16 batches. W = A-operand (rows = out-feat), h = B-operand (cols = batch).
// W k-slices 0..11 in VGPRs (192/lane), slices 12..15 in LDS (128KB).
// h in LDS [16 batch][512 feat] bf16, XOR-swizzled (byte ^= (b&7)<<4).
__global__ __launch_bounds__(512, 2) void rec_kern(
    const ushort* __restrict__ XU,   // [B*S, H] bf16, row = b*S + t  (U_b+W_b folded in)
    const ushort* __restrict__ Wb,   // [H, H] bf16 row-major
    ushort* __restrict__ Hst)        // [B*S, H] bf16
{
  extern __shared__ char smem[];     // [0,16K): h   [16K, 16K+128K): W slices 12..15
  const int tid = threadIdx.x;
  const int lane = tid & 63;
  const int wave = tid >> 6;         // 0..7
  const int b = lane & 15;
  const int hi = lane >> 4;          // 0..3
  const int bg = blockIdx.x << 4;
  const int swz = (b & 7) << 4;

  // stage W slices 12..15 -> LDS fragments [(s-12)][mt][lane*16]
  #pragma unroll
  for (int i = 0; i < 16; ++i) {
    const int ch = wave * 16 + i;          // 0..127
    const int s = 12 + (ch >> 5);
    const int mt = ch & 31;
    const ushort* src = Wb + (size_t)(mt * 16 + b) * H_ + s * 32 + hi * 8;
    gll16(src, smem + 16384 + (size_t)(s - 12) * 32768 + mt * 1024);
  }
  // zero h region (h_{-1} = 0)
  {
    f32x4 zz = 0.0f;
    *(f32x4*)(smem + tid * 32) = zz;
    *(f32x4*)(smem + tid * 32 + 16) = zz;
  }
  // W registers: slices 0..11 for this wave's 4 m-tiles
  short8 wreg[4][12];
  #pragma unroll
  for (int mt = 0; mt < 4; ++mt) {
    const int mtg = wave * 4 + mt;
    const ushort* wrow = Wb + (size_t)(mtg * 16 + b) * H_ + hi * 8;
    #pragma unroll
    for (int s = 0; s < 12; ++s)
      wreg[mt][s] = *(const short8*)(wrow + s * 32);
  }
  __syncthreads();

  const ushort* xurow = XU + (size_t)(bg + b) * S_ * H_;
  ushort* hrow = Hst + (size_t)(bg + b) * S_ * H_;

  for (int t = 0; t < S_; ++t) {
    // issue xu loads now; consumed after the barrier (~2.5k cycles later)
    uint2 xu[4];
    #pragma unroll
    for (int mt = 0; mt < 4; ++mt) {
      const int f0 = (wave * 4 + mt) * 16 + hi * 4;
      xu[mt] = *(const uint2*)(xurow + (size_t)t * H_ + f0);
    }
    f32x4 acc[4] = {};
    #pragma unroll
    for (int s = 0; s < 16; ++s) {
      const short8 bfrag = *(const short8*)(smem + b * 1024 + ((s * 64 + hi * 16) ^ swz));
      #pragma unroll
      for (int mt = 0; mt < 4; ++mt) {
        short8 w;
        if (s < 12) w = wreg[mt][s];
        else w = *(const short8*)(smem + 16384 + (s - 12) * 32768 + (wave * 4 + mt) * 1024 + lane * 16);
        acc[mt] = __builtin_amdgcn_mfma_f32_16x16x32_bf16(w, bfrag, acc[mt], 0, 0, 0);
      }
    }
    __syncthreads();  // all B-frag reads of h_{t-1} complete
    #pragma unroll
    for (int mt = 0; mt < 4; ++mt) {
      const int f0 = (wave * 4 + mt) * 16 + hi * 4;
      ushort4 hp;
      #pragma unroll
      for (int r = 0; r < 4; ++r) {
        const ushort xb = ((const ushort*)&xu[mt])[r];
        const float a = acc[mt][r] + bf16_f(xb);
        ((ushort*)&hp)[r] = bf16_rne(tanh_fast(a));
      }
      *(uint2*)(smem + b * 1024 + ((f0 * 2) ^ swz)) = *(uint2*)&hp;         // h for next step
      *(uint2*)(hrow + (size_t)t * H_ + f0) = *(uint2*)&hp;                 // h for V-GEMM
    }
    __syncthreads();  // h_t visible before next step's reads
  }
}

// ---------- launcher ----------
extern "C" void kernel_launch(void* const* d_in, const int* in_sizes, int n_in,
                              void* d_out, int out_size, void* d_ws, size_t ws_size,
                              hipStream_t stream) {
  const float* x     = (const float*)d_in[0];
  const float* U_w   = (const float*)d_in[1];
  const float* U_b   = (const float*)d_in[2];
  const float* W_w   = (const float*)d_in[3];
  const float* W_b   = (const float*)d_in[4];
  const float* V_w   = (const float*)d_in[5];
  const float* V_b   = (const float*)d_in[6];
  const float* fc1_w = (const float*)d_in[7];
  const float* fc1_b = (const float*)d_in[8];
  const float* fc2_w = (const float*)d_in[9];
  const float* fc2_b = (const float*)d_in[10];
  const float* fc3_w = (const float*)d_in[11];
  const float* fc3_b = (const float*)d_in[12];

  char* ws = (char*)d_ws;
  // ws layout: [0,64M): Hst / z2   [64M,128M): x_bf16 then o   [128M, +2.6M): bf16 weights
  ushort* Hst  = (ushort*)ws;                               // 67,108,864 B
  ushort* ws2  = (ushort*)(ws + 67108864);                  // 67,108,864 B
  ushort* wbuf = (ushort*)(ws + 134217728);
  ushort* U_wb = wbuf;                  // 131072 elems
  ushort* W_wb = U_wb + 131072;         // 262144
  ushort* V_wb = W_wb + 262144;
  ushort* f1b  = V_wb + 262144;
  ushort* f2b  = f1b + 262144;
  ushort* f3b  = f2b + 262144;
  float* cbias = (float*)(f3b + 131072); // 512 f32 = U_b + W_b
  ushort* bufA = (ushort*)d_out;         // 67,108,864 B: XU, later z1 (finally fp32 out)

  // converts (bf16 staging)
  cvt_kern<<<2048, 256, 0, stream>>>(x, ws2, (long)M_ * I_);
  cvt_kern<<<128, 256, 0, stream>>>(U_w, U_wb, (long)H_ * I_);
  cvt_kern<<<256, 256, 0, stream>>>(W_w, W_wb, (long)H_ * H_);
  cvt_kern<<<256, 256, 0, stream>>>(V_w, V_wb, (long)H_ * H_);
  cvt_kern<<<256, 256, 0, stream>>>(fc1_w, f1b, (long)H_ * H_);
  cvt_kern<<<256, 256, 0, stream>>>(fc2_w, f2b, (long)H_ * H_);
  cvt_kern<<<128, 256, 0, stream>>>(fc3_w, f3b, (long)O_ * H_);
  biascomb_kern<<<1, 512, 0, stream>>>(U_b, W_b, cbias);

  // G0: XU = x @ U^T + (U_b + W_b)   -> bufA (d_out as bf16 scratch)
  gemm_kern<false><<<dim3(512 * 4), 256, 0, stream>>>(ws2, U_wb, cbias, bufA, M_, H_, I_);

  // recurrence -> Hst
  hipFuncSetAttribute((const void*)rec_kern, hipFuncAttributeMaxDynamicSharedMemorySize, 147456);
  rec_kern<<<dim3(4), dim3(512), 147456, stream>>>(bufA, W_wb, Hst);

  // o = Hst @ V^T + V_b -> ws2
  gemm_kern<false><<<dim3(512 * 4), 256, 0, stream>>>(Hst, V_wb, V_b, ws2, M_, H_, H_);
  // z1 = o @ fc1^T + b1 -> bufA
  gemm_kern<false><<<dim3(512 * 4), 256, 0, stream>>>(ws2, f1b, fc1_b, bufA, M_, H_, H_);
  // z2 = z1 @ fc2^T + b2 -> Hst (dead)
  gemm_kern<false><<<dim3(512 * 4), 256, 0, stream>>>(bufA, f2b, fc2_b, Hst, M_, H_, H_);
  // out = z2 @ fc3^T + b3 -> d_out fp32 [B,S,O]
  gemm_kern<true><<<dim3(512 * 2), 256, 0, stream>>>(Hst, f3b, fc3_b, d_out, M_, O_, H_);

  (void)in_sizes; (void)n_in; (void)out_size; (void)ws_size;
}

// Round 2
// 2817.624 us; speedup vs baseline: 1.2084x; 1.2084x over previous
//
#include <hip/hip_runtime.h>
#include <hip/hip_bf16.h>

typedef __attribute__((ext_vector_type(8))) short short8;
typedef __attribute__((ext_vector_type(4))) float f32x4;

#define B_ 64
#define S_ 1024
#define I_ 256
#define H_ 512
#define O_ 256
#define M_ (B_ * S_)   // 65536 rows everywhere

// ---------- helpers ----------
__device__ __forceinline__ ushort bf16_rne(float f) {
  unsigned u = __float_as_uint(f);
  return (ushort)((u + 0x7FFFu + ((u >> 16) & 1u)) >> 16);
}
__device__ __forceinline__ float bf16_f(ushort s) {
  return __uint_as_float(((unsigned)s) << 16);
}
__device__ __forceinline__ void gll16(const void* g, void* l) {
  __builtin_amdgcn_global_load_lds((const __attribute__((address_space(1))) void*)g,
                                   (__attribute__((address_space(3))) void*)l, 16, 0, 0);
}
__device__ __forceinline__ float tanh_fast(float a) {
  a = fminf(fmaxf(a, -9.0f), 9.0f);
#if __has_builtin(__builtin_amdgcn_exp2f)
  float t = __builtin_amdgcn_exp2f(a * 2.8853900817779268f); // e^(2a)
#else
  float t = exp2f(a * 2.8853900817779268f);
#endif
#if __has_builtin(__builtin_amdgcn_rcpf)
  return (t - 1.0f) * __builtin_amdgcn_rcpf(t + 1.0f);
#else
  return (t - 1.0f) / (t + 1.0f);
#endif
}

// ---------- fp32 -> bf16 convert ----------
__global__ void cvt_kern(const float* __restrict__ in, ushort* __restrict__ out, long n) {
  long i = ((long)blockIdx.x * blockDim.x + threadIdx.x) * 4;
  const long stride = (long)gridDim.x * blockDim.x * 4;
  for (; i < n; i += stride) {
    const float4 v = *(const float4*)(in + i);
    ushort4 o;
    o.x = bf16_rne(v.x); o.y = bf16_rne(v.y); o.z = bf16_rne(v.z); o.w = bf16_rne(v.w);
    *(ushort4*)(out + i) = o;
  }
}

__global__ void biascomb_kern(const float* __restrict__ a, const float* __restrict__ b,
                              float* __restrict__ o) {
  int i = threadIdx.x;
  o[i] = a[i] + b[i];
}

// ---------- small fp32 GEMM: C[M,N] = A[M,K] @ B[K,N], row-major ----------
__global__ __launch_bounds__(256) void f32gemm_kern(
    const float* __restrict__ A, const float* __restrict__ Bm,
    float* __restrict__ C, int M, int N, int K)
{
  __shared__ float As[16][16];
  __shared__ float Bs[16][17];
  const int tx = threadIdx.x & 15, ty = threadIdx.x >> 4;
  const int row = blockIdx.y * 16 + ty, col = blockIdx.x * 16 + tx;
  float acc = 0.0f;
  for (int k0 = 0; k0 < K; k0 += 16) {
    As[ty][tx] = A[(size_t)row * K + k0 + tx];
    Bs[ty][tx] = Bm[(size_t)(k0 + ty) * N + col];
    __syncthreads();
    #pragma unroll
    for (int kk = 0; kk < 16; ++kk) acc += As[ty][kk] * Bs[kk][tx];
    __syncthreads();
  }
  C[(size_t)row * N + col] = acc;
}

// ---------- matvec: y = M@x + b (fp32, M [R,C] row-major) ----------
__global__ void matvec_kern(const float* __restrict__ Mw, const float* __restrict__ x,
                            const float* __restrict__ b, float* __restrict__ y, int R, int C) {
  const int i = blockIdx.x * blockDim.x + threadIdx.x;
  if (i >= R) return;
  float acc = b[i];
  for (int k = 0; k < C; ++k) acc += Mw[(size_t)i * C + k] * x[k];
  y[i] = acc;
}

// ---------- GEMM: C[M,N] = A[M,K] @ Wt[N,K]^T + bias ----------
// 128x128 tile, BK=32, 4 waves (2x2), 16x16x32 bf16 MFMA, global_load_lds staging.
template<bool OUT_F32>
__global__ __launch_bounds__(256) void gemm_kern(
    const ushort* __restrict__ A, const ushort* __restrict__ Wt,
    const float* __restrict__ bias, void* __restrict__ out,
    int M, int N, int K)
{
  __shared__ char smem[16384];   // [0,8K): A tile  [8K,16K): B tile; layout [kgrp][row][16B]
  const int tid = threadIdx.x;
  const int lane = tid & 63, wave = tid >> 6;
  const int wm = wave >> 1, wn = wave & 1;
  const int nt = N >> 7;
  const int bm = blockIdx.x / nt, bn = blockIdx.x % nt;
  const long m0 = (long)bm * 128, n0 = (long)bn * 128;

  f32x4 acc[4][4] = {};
  const int KT = K >> 5;
  for (int kt = 0; kt < KT; ++kt) {
    #pragma unroll
    for (int i = 0; i < 4; ++i) {
      const int c = wave * 4 + i;         // 0..15
      const int isB = c >> 3;
      const int cc = c & 7;
      const int kgrp = cc >> 1, rhalf = cc & 1;
      const int row = rhalf * 64 + lane;
      const ushort* src = (isB ? Wt + (n0 + row) * (long)K : A + (m0 + row) * (long)K)
                          + (long)kt * 32 + kgrp * 8;
      gll16(src, smem + isB * 8192 + kgrp * 2048 + rhalf * 1024);
    }
    __syncthreads();
    const char* Ab = smem + (lane >> 4) * 2048;
    const char* Bb = smem + 8192 + (lane >> 4) * 2048;
    short8 af[4], bf[4];
    #pragma unroll
    for (int i = 0; i < 4; ++i) {
      af[i] = *(const short8*)(Ab + (wm * 64 + i * 16 + (lane & 15)) * 16);
      bf[i] = *(const short8*)(Bb + (wn * 64 + i * 16 + (lane & 15)) * 16);
    }
    #pragma unroll
    for (int mi = 0; mi < 4; ++mi)
      #pragma unroll
      for (int ni = 0; ni < 4; ++ni)
        acc[mi][ni] = __builtin_amdgcn_mfma_f32_16x16x32_bf16(af[mi], bf[ni], acc[mi][ni], 0, 0, 0);
    __syncthreads();
  }
  #pragma unroll
  for (int ni = 0; ni < 4; ++ni) {
    const long n = n0 + wn * 64 + ni * 16 + (lane & 15);
    const float bv = bias[n];
    #pragma unroll
    for (int mi = 0; mi < 4; ++mi) {
      const long mrow = m0 + wm * 64 + mi * 16 + (lane >> 4) * 4;
      #pragma unroll
      for (int r = 0; r < 4; ++r) {
        const float v = acc[mi][ni][r] + bv;
        if (OUT_F32) ((float*)out)[(mrow + r) * (long)N + n] = v;
        else         ((ushort*)out)[(mrow + r) * (long)N + n] = bf16_rne(v);
      }
    }
  }
}

// ---------- recurrence: h_t = tanh(xu_t + W h_{t-1}) ----------
// 4 WGs x 16 batches. W = A-operand (rows = out-feat), h = B-operand (cols = batch).
// W k-slices 0..11 pinned in VGPRs (asm keep-alive), slices 12..15 in LDS (128KB).
// h ping-pong in LDS [2][16 batch][512 feat] bf16, XOR-swizzled -> 1 barrier/step.
__global__ __launch_bounds__(512, 2) void rec_kern(
    const ushort* __restrict__ XU,   // [B*S, H] bf16, row = b*S + t  (U_b+W_b folded in)
    const ushort* __restrict__ Wb,   // [H, H] bf16 row-major
    ushort* __restrict__ Hst)        // [B*S, H] bf16
{
  extern __shared__ char smem[];     // [0,32K): h pingpong   [32K, 160K): W slices 12..15
  const int tid = threadIdx.x;
  const int lane = tid & 63;
  const int wave = tid >> 6;         // 0..7
  const int b = lane & 15;
  const int hi = lane >> 4;          // 0..3
  const int bg = blockIdx.x << 4;
  const int swz = (b & 7) << 4;

  // stage W slices 12..15 -> LDS fragments [(s-12)][mtg][lane*16]
  #pragma unroll
  for (int i = 0; i < 16; ++i) {
    const int ch = wave * 16 + i;          // 0..127
    const int s = 12 + (ch >> 5);
    const int mt = ch & 31;
    const ushort* src = Wb + (size_t)(mt * 16 + b) * H_ + s * 32 + hi * 8;
    gll16(src, smem + 32768 + (size_t)(s - 12) * 32768 + mt * 1024);
  }
  // zero both h buffers (h_{-1} = 0 in buf 0)
  {
    f32x4 zz = 0.0f;
    *(f32x4*)(smem + tid * 64) = zz;
    *(f32x4*)(smem + tid * 64 + 16) = zz;
    *(f32x4*)(smem + tid * 64 + 32) = zz;
    *(f32x4*)(smem + tid * 64 + 48) = zz;
  }
  // W registers: slices 0..11 for this wave's 4 m-tiles, pinned live via asm
  short8 wreg[4][12];
  #pragma unroll
  for (int mt = 0; mt < 4; ++mt) {
    const int mtg = wave * 4 + mt;
    const ushort* wrow = Wb + (size_t)(mtg * 16 + b) * H_ + hi * 8;
    #pragma unroll
    for (int s = 0; s < 12; ++s)
      wreg[mt][s] = *(const short8*)(wrow + s * 32);
  }
  #pragma unroll
  for (int mt = 0; mt < 4; ++mt)
    #pragma unroll
    for (int s = 0; s < 12; ++s)
      asm volatile("" : "+v"(wreg[mt][s]));
  __syncthreads();

  const ushort* xup = XU + (size_t)(bg + b) * S_ * H_ + wave * 64 + hi * 4;
  ushort* hgp = Hst + (size_t)(bg + b) * S_ * H_ + wave * 64 + hi * 4;
  const int hoff = b * 1024;                     // within h buffer
  const int woff = (wave * 128 + hi * 8);        // epilogue LDS write base (bytes, pre-XOR)

  for (int t = 0; t < S_; ++t) {
    // issue xu loads now; consumed in the epilogue (~2.5k cycles later)
    uint2 xu[4];
    #pragma unroll
    for (int mt = 0; mt < 4; ++mt)
      xu[mt] = *(const uint2*)(xup + mt * 16);
    xup += H_;

    const char* hb = smem + (t & 1) * 16384 + hoff;    // h_{t-1}
    f32x4 acc[4] = {};
    #pragma unroll
    for (int s = 0; s < 16; ++s) {
      const short8 bfrag = *(const short8*)(hb + ((s * 64 + hi * 16) ^ swz));
      #pragma unroll
      for (int mt = 0; mt < 4; ++mt) {
        short8 w;
        if (s < 12) w = wreg[mt][s];
        else w = *(const short8*)(smem + 32768 + (s - 12) * 32768 + (wave * 4 + mt) * 1024 + lane * 16);
        acc[mt] = __builtin_amdgcn_mfma_f32_16x16x32_bf16(w, bfrag, acc[mt], 0, 0, 0);
      }
    }
    // epilogue: h_t = tanh(acc + xu); write to other h buffer + global
    char* hw = smem + ((t + 1) & 1) * 16384 + hoff;
    #pragma unroll
    for (int mt = 0; mt < 4; ++mt) {
      ushort4 hp;
      #pragma unroll
      for (int r = 0; r < 4; ++r) {
        const ushort xb = ((const ushort*)&xu[mt])[r];
        const float a = acc[mt][r] + bf16_f(xb);
        ((ushort*)&hp)[r] = bf16_rne(tanh_fast(a));
      }
      *(uint2*)(hw + ((woff + mt * 32) ^ swz)) = *(uint2*)&hp;   // h for next step
      *(uint2*)(hgp + mt * 16) = *(uint2*)&hp;                   // h for head GEMM
    }
    hgp += H_;
    __syncthreads();  // h_t visible (and h_{t-1} reads done) before next step
  }
}

// ---------- launcher ----------
extern "C" void kernel_launch(void* const* d_in, const int* in_sizes, int n_in,
                              void* d_out, int out_size, void* d_ws, size_t ws_size,
                              hipStream_t stream) {
  const float* x     = (const float*)d_in[0];
  const float* U_w   = (const float*)d_in[1];
  const float* U_b   = (const float*)d_in[2];
  const float* W_w   = (const float*)d_in[3];
  const float* W_b   = (const float*)d_in[4];
  const float* V_w   = (const float*)d_in[5];
  const float* V_b   = (const float*)d_in[6];
  const float* fc1_w = (const float*)d_in[7];
  const float* fc1_b = (const float*)d_in[8];
  const float* fc2_w = (const float*)d_in[9];
  const float* fc2_b = (const float*)d_in[10];
  const float* fc3_w = (const float*)d_in[11];
  const float* fc3_b = (const float*)d_in[12];

  char* ws = (char*)d_ws;
  // ws layout: [0,64M): Hst   [64M,96M): x_bf16   [128M, +~4M): weights/scratch
  ushort* Hst  = (ushort*)ws;                               // 67,108,864 B
  ushort* xb16 = (ushort*)(ws + 67108864);                  // 33,554,432 B
  char*   wb   = ws + 134217728;
  ushort* U_wb = (ushort*)wb;                    // 512*256  = 131072 elems (256KB)
  ushort* W_wb = U_wb + 131072;                  // 512*512  = 262144 (512KB)
  ushort* Wcb  = W_wb + 262144;                  // 256*512  = 131072 (256KB)
  float*  C1   = (float*)(Wcb + 131072);         // 512*512 f32 (1MB)
  float*  C2   = C1 + 262144;                    // 512*512 f32 (1MB)
  float*  Wcf  = C2 + 262144;                    // 256*512 f32 (512KB)
  float*  cbias = Wcf + 131072;                  // 512 f32
  float*  t1   = cbias + 512;                    // 512 f32
  float*  t2   = t1 + 512;                       // 512 f32
  float*  bc   = t2 + 512;                       // 256 f32
  ushort* bufA = (ushort*)d_out;                 // XU scratch (bf16), then fp32 out

  // bf16 staging converts
  cvt_kern<<<2048, 256, 0, stream>>>(x, xb16, (long)M_ * I_);
  cvt_kern<<<128, 256, 0, stream>>>(U_w, U_wb, (long)H_ * I_);
  cvt_kern<<<256, 256, 0, stream>>>(W_w, W_wb, (long)H_ * H_);
  biascomb_kern<<<1, 512, 0, stream>>>(U_b, W_b, cbias);

  // fused head weights (fp32): C1 = fc1@V, C2 = fc2@C1, Wc = fc3@C2
  f32gemm_kern<<<dim3(32, 32), 256, 0, stream>>>(fc1_w, V_w, C1, H_, H_, H_);
  f32gemm_kern<<<dim3(32, 32), 256, 0, stream>>>(fc2_w, C1, C2, H_, H_, H_);
  f32gemm_kern<<<dim3(32, 16), 256, 0, stream>>>(fc3_w, C2, Wcf, O_, H_, H_);
  // bias chain: bc = fc3@(fc2@(fc1@V_b + b1) + b2) + b3
  matvec_kern<<<2, 256, 0, stream>>>(fc1_w, V_b, fc1_b, t1, H_, H_);
  matvec_kern<<<2, 256, 0, stream>>>(fc2_w, t1, fc2_b, t2, H_, H_);
  matvec_kern<<<1, 256, 0, stream>>>(fc3_w, t2, fc3_b, bc, O_, H_);
  cvt_kern<<<128, 256, 0, stream>>>(Wcf, Wcb, (long)O_ * H_);

  // G0: XU = x @ U^T + (U_b + W_b)   -> bufA (d_out as bf16 scratch)
  gemm_kern<false><<<dim3(512 * 4), 256, 0, stream>>>(xb16, U_wb, cbias, bufA, M_, H_, I_);

  // recurrence -> Hst
  hipFuncSetAttribute((const void*)rec_kern, hipFuncAttributeMaxDynamicSharedMemorySize, 163840);
  rec_kern<<<dim3(4), dim3(512), 163840, stream>>>(bufA, W_wb, Hst);

  // head: out = Hst @ Wc^T + bc -> d_out fp32 [B,S,O]
  gemm_kern<true><<<dim3(512 * 2), 256, 0, stream>>>(Hst, Wcb, bc, d_out, M_, O_, H_);

  (void)in_sizes; (void)n_in; (void)out_size; (void)ws_size;
}